// Round 1
// baseline (109.078 us; speedup 1.0000x reference)
//
#include <hip/hip_runtime.h>
#include <hip/hip_bf16.h>

#define NS   16384
#define FKD  2048
#define CD   100
#define CP   112
#define MT   64
#define EPSF 1e-8f

typedef float f32x4 __attribute__((ext_vector_type(4)));
typedef short bf16x8 __attribute__((ext_vector_type(8)));

__device__ inline unsigned short f2bf(float f) {
    unsigned int u = __float_as_uint(f);
    u += 0x7FFFu + ((u >> 16) & 1u);   // RNE; inputs are finite in [0,1]
    return (unsigned short)(u >> 16);
}

// GEMM: S_partial[kc][m][c] = sum over k-chunk of bf16(mem[n][m]) * bf16(B[n][c])
// B = teacher padded to 112 cols; col 100 == 1.0 (gives bin_mass), 101..111 == 0.
__global__ __launch_bounds__(256, 2) void ebl_gemm(
    const float* __restrict__ mem, const float* __restrict__ tp,
    float* __restrict__ spart, int steps)
{
    __shared__ unsigned short A_lds[4 * MT * 8];   // [g][m][j]  j = k-within-group
    __shared__ unsigned short B_lds[4 * CP * 8];   // [g][c][j]

    const int t  = threadIdx.x;
    const int w  = t >> 6;          // wave 0..3  -> m rows [w*16, w*16+16)
    const int l  = t & 63;
    const int lg = l >> 4, lr = l & 15;
    const int m0 = blockIdx.x * MT;
    const int kc = blockIdx.y;

    // A staging role: thread -> (g, m)
    const int ga = t >> 6, ma = t & 63;
    // B staging roles: two linear ids over 4*112 = 448 (g, c) slots
    const int idx0 = t;
    const int idx1 = t + 256;
    const int g0 = idx0 / CP, c0 = idx0 - g0 * CP;
    const int g1 = idx1 / CP, c1 = idx1 - g1 * CP;

    f32x4 acc[7];
    #pragma unroll
    for (int i = 0; i < 7; ++i) acc[i] = (f32x4){0.f, 0.f, 0.f, 0.f};

    const long u_base = (long)kc * steps * 32;

    for (int s = 0; s < steps; ++s) {
        const long u0 = u_base + (long)s * 32;

        // ---- global -> regs (fp32), overlap with previous compute ----
        float av[8];
        const float* ap = mem + (u0 + (long)ga * 8) * FKD + m0 + ma;
        #pragma unroll
        for (int j = 0; j < 8; ++j) av[j] = ap[(long)j * FKD];

        float bv0[8];
        const float* bp0 = tp + (u0 + (long)g0 * 8) * CD + c0;
        #pragma unroll
        for (int j = 0; j < 8; ++j)
            bv0[j] = (c0 < CD) ? bp0[(long)j * CD] : (c0 == CD ? 1.0f : 0.0f);

        float bv1[8];
        if (idx1 < 448) {
            const float* bp1 = tp + (u0 + (long)g1 * 8) * CD + c1;
            #pragma unroll
            for (int j = 0; j < 8; ++j)
                bv1[j] = (c1 < CD) ? bp1[(long)j * CD] : (c1 == CD ? 1.0f : 0.0f);
        }

        __syncthreads();   // previous iteration's frag reads complete

        // ---- regs -> LDS (bf16, fragment-friendly layout) ----
        {
            uint4 p;
            p.x = (unsigned)f2bf(av[0]) | ((unsigned)f2bf(av[1]) << 16);
            p.y = (unsigned)f2bf(av[2]) | ((unsigned)f2bf(av[3]) << 16);
            p.z = (unsigned)f2bf(av[4]) | ((unsigned)f2bf(av[5]) << 16);
            p.w = (unsigned)f2bf(av[6]) | ((unsigned)f2bf(av[7]) << 16);
            *reinterpret_cast<uint4*>(&A_lds[(ga * MT + ma) * 8]) = p;
        }
        {
            uint4 p;
            p.x = (unsigned)f2bf(bv0[0]) | ((unsigned)f2bf(bv0[1]) << 16);
            p.y = (unsigned)f2bf(bv0[2]) | ((unsigned)f2bf(bv0[3]) << 16);
            p.z = (unsigned)f2bf(bv0[4]) | ((unsigned)f2bf(bv0[5]) << 16);
            p.w = (unsigned)f2bf(bv0[6]) | ((unsigned)f2bf(bv0[7]) << 16);
            *reinterpret_cast<uint4*>(&B_lds[(g0 * CP + c0) * 8]) = p;
        }
        if (idx1 < 448) {
            uint4 p;
            p.x = (unsigned)f2bf(bv1[0]) | ((unsigned)f2bf(bv1[1]) << 16);
            p.y = (unsigned)f2bf(bv1[2]) | ((unsigned)f2bf(bv1[3]) << 16);
            p.z = (unsigned)f2bf(bv1[4]) | ((unsigned)f2bf(bv1[5]) << 16);
            p.w = (unsigned)f2bf(bv1[6]) | ((unsigned)f2bf(bv1[7]) << 16);
            *reinterpret_cast<uint4*>(&B_lds[(g1 * CP + c1) * 8]) = p;
        }

        __syncthreads();

        // ---- fragments + MFMA ----
        bf16x8 af = *reinterpret_cast<const bf16x8*>(&A_lds[(lg * MT + w * 16 + lr) * 8]);
        #pragma unroll
        for (int nt = 0; nt < 7; ++nt) {
            bf16x8 bf = *reinterpret_cast<const bf16x8*>(&B_lds[(lg * CP + nt * 16 + lr) * 8]);
            acc[nt] = __builtin_amdgcn_mfma_f32_16x16x32_bf16(af, bf, acc[nt], 0, 0, 0);
        }
    }

    // ---- write partial S (C/D layout: col = lane&15, row = (lane>>4)*4 + reg) ----
    float* sp = spart + (size_t)kc * FKD * CP;
    #pragma unroll
    for (int nt = 0; nt < 7; ++nt) {
        const int c = nt * 16 + lr;
        #pragma unroll
        for (int r = 0; r < 4; ++r) {
            const int m = m0 + w * 16 + lg * 4 + r;
            sp[(size_t)m * CP + c] = acc[nt][r];
        }
    }
}

// Per-f loss partial: sum NK split-K partials, centroids, entropies.
__global__ __launch_bounds__(256) void ebl_epilogue(
    const float* __restrict__ spart, int NK, float* __restrict__ fpart)
{
    __shared__ float Ss[32 * CP];
    __shared__ float massL[32];
    __shared__ float red[4];
    const int t = threadIdx.x;
    const int f = blockIdx.x;

    for (int idx = t; idx < 32 * CP; idx += 256) {
        const size_t base = (size_t)(f * 32) * CP + idx;  // rows f*32..f*32+31 contiguous
        float s = 0.f;
        for (int p = 0; p < NK; ++p) s += spart[(size_t)p * FKD * CP + base];
        Ss[idx] = s;
    }
    __syncthreads();
    if (t < 32) massL[t] = Ss[t * CP + CD] + EPSF;  // ones-column = bin mass (+EPS)
    __syncthreads();

    float a_int = 0.f, a_mix = 0.f;
    for (int idx = t; idx < 32 * CD; idx += 256) {
        const int k = idx / CD, c = idx - k * CD;
        const float cent = Ss[k * CP + c] / massL[k];
        a_int -= cent * logf(cent + EPSF) * massL[k];
    }
    for (int idx = t; idx < 31 * CD; idx += 256) {
        const int k = idx / CD, c = idx - k * CD;
        const float mix = 0.5f * (Ss[k * CP + c] / massL[k] + Ss[(k + 1) * CP + c] / massL[k + 1]);
        a_mix += mix * logf(mix + EPSF);
    }

    float part = a_int * (1.0f / (float)NS) + 0.5f * a_mix;
    #pragma unroll
    for (int off = 32; off > 0; off >>= 1) part += __shfl_down(part, off);
    if ((t & 63) == 0) red[t >> 6] = part;
    __syncthreads();
    if (t == 0) fpart[f] = (red[0] + red[1]) + (red[2] + red[3]);
}

__global__ void ebl_finalize(const float* __restrict__ fpart, float* __restrict__ out) {
    float v = fpart[threadIdx.x];
    #pragma unroll
    for (int off = 32; off > 0; off >>= 1) v += __shfl_down(v, off);
    if (threadIdx.x == 0) out[0] = v;
}

extern "C" void kernel_launch(void* const* d_in, const int* in_sizes, int n_in,
                              void* d_out, int out_size, void* d_ws, size_t ws_size,
                              hipStream_t stream)
{
    const float* mem = (const float*)d_in[0];
    const float* tp  = (const float*)d_in[1];
    float* out = (float*)d_out;

    // Split-K factor limited by workspace (partials are deterministic, no atomics).
    int NK = 16;
    while (NK > 1 && ((size_t)NK * FKD * CP + 64) * sizeof(float) > ws_size) NK >>= 1;
    const int steps = NS / (NK * 32);

    float* spart = (float*)d_ws;
    float* fpart = spart + (size_t)NK * FKD * CP;

    dim3 grid(FKD / MT, NK);
    ebl_gemm<<<grid, 256, 0, stream>>>(mem, tp, spart, steps);
    ebl_epilogue<<<64, 256, 0, stream>>>(spart, NK, fpart);
    ebl_finalize<<<1, 64, 0, stream>>>(fpart, out);
}

// Round 2
// 63.352 us; speedup vs baseline: 1.7218x; 1.7218x over previous
//
#include <hip/hip_runtime.h>
#include <hip/hip_bf16.h>

#define NS   16384
#define FKD  2048
#define CD   100
#define CP   112
#define MT   64
#define EPSF 1e-8f
#define SFK  (FKD * CP)          // 229376 elements of the reduced S matrix
#define NGRP (NS / 8)            // 2048 k-groups of 8

typedef float f32x4 __attribute__((ext_vector_type(4)));
typedef short bf16x8 __attribute__((ext_vector_type(8)));

__device__ inline unsigned short f2bf(float f) {
    unsigned int u = __float_as_uint(f);
    u += 0x7FFFu + ((u >> 16) & 1u);   // RNE; inputs are finite in [0,1]
    return (unsigned short)(u >> 16);
}

// ---------------- prep: teacher -> bf16 fragment layout ----------------
// Bp[g][c][j] = bf16(tp[(8g+j)*CD + c]) ; col CD == 1.0 (bin-mass column), >CD == 0
__global__ __launch_bounds__(256) void ebl_prep(
    const float* __restrict__ tp, unsigned short* __restrict__ Bp)
{
    const int idx = blockIdx.x * 256 + threadIdx.x;     // (g, c)
    if (idx >= NGRP * CP) return;
    const int g = idx / CP, c = idx - g * CP;
    unsigned short v[8];
    if (c < CD) {
        const float* p = tp + (size_t)g * 8 * CD + c;
        #pragma unroll
        for (int j = 0; j < 8; ++j) v[j] = f2bf(p[(size_t)j * CD]);
    } else {
        const unsigned short fill = (c == CD) ? 0x3F80 : 0;   // bf16(1.0) / 0
        #pragma unroll
        for (int j = 0; j < 8; ++j) v[j] = fill;
    }
    *reinterpret_cast<uint4*>(Bp + (size_t)idx * 8) = *reinterpret_cast<const uint4*>(v);
}

// ---------------- GEMM: barrier-free, fragments direct from memory ----------------
// S_partial[kc][m][c] = sum over k-chunk of bf16(mem[n][m]) * Bp[n][c]
__global__ __launch_bounds__(256, 4) void ebl_gemm(
    const float* __restrict__ mem, const unsigned short* __restrict__ Bp,
    float* __restrict__ spart, int steps)
{
    const int t  = threadIdx.x;
    const int w  = t >> 6;                 // wave -> m-subtile
    const int l  = t & 63;
    const int lg = l >> 4, lr = l & 15;
    const int m  = blockIdx.x * MT + w * 16 + lr;
    const int kc = blockIdx.y;
    const int g0 = kc * steps * 4 + lg;    // this lane's first k-group

    const float*          ap = mem + (size_t)g0 * 8 * FKD + m;
    const unsigned short* bp = Bp + ((size_t)g0 * CP + lr) * 8;

    f32x4 acc[7];
    #pragma unroll
    for (int i = 0; i < 7; ++i) acc[i] = (f32x4){0.f, 0.f, 0.f, 0.f};

    float  aC[8]; bf16x8 bC[7];
    #pragma unroll
    for (int j = 0; j < 8; ++j) aC[j] = ap[(size_t)j * FKD];
    #pragma unroll
    for (int nt = 0; nt < 7; ++nt)
        bC[nt] = *reinterpret_cast<const bf16x8*>(bp + nt * 128);   // 16 c-rows * 8

    for (int s = 0; s < steps - 1; ++s) {
        const float*          ap2 = ap + (size_t)32 * FKD;
        const unsigned short* bp2 = bp + 4 * CP * 8;
        float  aN[8]; bf16x8 bN[7];
        #pragma unroll
        for (int j = 0; j < 8; ++j) aN[j] = ap2[(size_t)j * FKD];
        #pragma unroll
        for (int nt = 0; nt < 7; ++nt)
            bN[nt] = *reinterpret_cast<const bf16x8*>(bp2 + nt * 128);

        bf16x8 af;
        #pragma unroll
        for (int j = 0; j < 8; ++j) af[j] = (short)f2bf(aC[j]);
        #pragma unroll
        for (int nt = 0; nt < 7; ++nt)
            acc[nt] = __builtin_amdgcn_mfma_f32_16x16x32_bf16(af, bC[nt], acc[nt], 0, 0, 0);

        ap = ap2; bp = bp2;
        #pragma unroll
        for (int j = 0; j < 8; ++j) aC[j] = aN[j];
        #pragma unroll
        for (int nt = 0; nt < 7; ++nt) bC[nt] = bN[nt];
    }
    {
        bf16x8 af;
        #pragma unroll
        for (int j = 0; j < 8; ++j) af[j] = (short)f2bf(aC[j]);
        #pragma unroll
        for (int nt = 0; nt < 7; ++nt)
            acc[nt] = __builtin_amdgcn_mfma_f32_16x16x32_bf16(af, bC[nt], acc[nt], 0, 0, 0);
    }

    // C/D layout: col = lane&15, row = (lane>>4)*4 + reg   [verified round 1]
    float* sp = spart + (size_t)kc * SFK;
    #pragma unroll
    for (int nt = 0; nt < 7; ++nt) {
        const int c = nt * 16 + lr;
        #pragma unroll
        for (int r = 0; r < 4; ++r) {
            const int mm = blockIdx.x * MT + w * 16 + lg * 4 + r;
            sp[(size_t)mm * CP + c] = acc[nt][r];
        }
    }
}

// ---------------- reduce split-K partials (fully parallel, coalesced) ----------------
__global__ __launch_bounds__(256) void ebl_reduce(
    const float* __restrict__ spart, float* __restrict__ S, int NK)
{
    const int idx = blockIdx.x * 256 + threadIdx.x;
    if (idx >= SFK) return;
    float s = 0.f;
    for (int p = 0; p < NK; ++p) s += spart[(size_t)p * SFK + idx];
    S[idx] = s;
}

// ---------------- entropies per f, partial losses ----------------
__global__ __launch_bounds__(256) void ebl_entropy(
    const float* __restrict__ S, float* __restrict__ fpart)
{
    __shared__ float Ss[32 * CP];
    __shared__ float massL[32];
    __shared__ float red[4];
    const int t = threadIdx.x;
    const int f = blockIdx.x;

    for (int idx = t; idx < 32 * CP; idx += 256)
        Ss[idx] = S[(size_t)f * 32 * CP + idx];
    __syncthreads();
    if (t < 32) massL[t] = Ss[t * CP + CD] + EPSF;   // ones-column = bin mass (+EPS)
    __syncthreads();

    float a_int = 0.f, a_mix = 0.f;
    for (int idx = t; idx < 32 * CD; idx += 256) {
        const int k = idx / CD, c = idx - k * CD;
        const float cent = Ss[k * CP + c] / massL[k];
        a_int -= cent * logf(cent + EPSF) * massL[k];
    }
    for (int idx = t; idx < 31 * CD; idx += 256) {
        const int k = idx / CD, c = idx - k * CD;
        const float mix = 0.5f * (Ss[k * CP + c] / massL[k] + Ss[(k + 1) * CP + c] / massL[k + 1]);
        a_mix += mix * logf(mix + EPSF);
    }

    float part = a_int * (1.0f / (float)NS) + 0.5f * a_mix;
    #pragma unroll
    for (int off = 32; off > 0; off >>= 1) part += __shfl_down(part, off);
    if ((t & 63) == 0) red[t >> 6] = part;
    __syncthreads();
    if (t == 0) fpart[f] = (red[0] + red[1]) + (red[2] + red[3]);
}

__global__ void ebl_finalize(const float* __restrict__ fpart, float* __restrict__ out) {
    float v = fpart[threadIdx.x];
    #pragma unroll
    for (int off = 32; off > 0; off >>= 1) v += __shfl_down(v, off);
    if (threadIdx.x == 0) out[0] = v;
}

extern "C" void kernel_launch(void* const* d_in, const int* in_sizes, int n_in,
                              void* d_out, int out_size, void* d_ws, size_t ws_size,
                              hipStream_t stream)
{
    const float* mem = (const float*)d_in[0];
    const float* tp  = (const float*)d_in[1];
    float* out = (float*)d_out;

    const size_t bpBytes = (size_t)NGRP * CP * 8 * 2;    // 3,670,016 B (256-aligned)

    int NK = 32;
    while (NK > 1 && bpBytes + ((size_t)NK * SFK + SFK + 64) * 4 > ws_size) NK >>= 1;
    const int steps = NS / (NK * 32);

    unsigned short* Bp = (unsigned short*)d_ws;
    float* spart = (float*)((char*)d_ws + bpBytes);
    float* S     = spart + (size_t)NK * SFK;
    float* fpart = S + SFK;

    ebl_prep<<<(NGRP * CP + 255) / 256, 256, 0, stream>>>(tp, Bp);
    dim3 grid(FKD / MT, NK);
    ebl_gemm<<<grid, 256, 0, stream>>>(mem, Bp, spart, steps);
    ebl_reduce<<<(SFK + 255) / 256, 256, 0, stream>>>(spart, S, NK);
    ebl_entropy<<<64, 256, 0, stream>>>(S, fpart);
    ebl_finalize<<<1, 64, 0, stream>>>(fpart, out);
}